// Round 3
// baseline (92.717 us; speedup 1.0000x reference)
//
#include <hip/hip_runtime.h>

// OneHotEncoder: per-row histogram of tokens, skipping pad_idx=0.
// tokens: [B=256, T=2048] int32 ; out: [B, VOCAB=32000] float32.
//
// V3: zero + scatter. The output is >93% zeros (<=2048 nonzero of 32000/row),
// so instead of building a per-row histogram in LDS and unpacking it (3
// barrier-separated phases throttling the store stream), we:
//   kernel 1: stream f32x4 zeros over the whole 32.8 MB output
//             (structurally identical to the 6.2 TB/s harness fill)
//   kernel 2: one device-scope atomicAdd(+1.0f) per non-pad token (~524K
//             atomics). Kernel 1's end-of-kernel L2 writeback leaves the
//             output lines in the memory-side Infinity Cache, so these are
//             L3-resident RMWs, not HBM round-trips.
// Duplicate tokens in a row are handled by the atomics; column 0 stays zero
// because pad tokens are skipped.

#define VOCAB 32000
#define BLOCK 256

typedef float f32x4 __attribute__((ext_vector_type(4)));

__global__ __launch_bounds__(BLOCK)
void OneHotEncoder_43052752175267_zero(float* __restrict__ out, int n4) {
    f32x4* o4 = (f32x4*)out;
    const f32x4 z = {0.f, 0.f, 0.f, 0.f};
    const int stride = gridDim.x * BLOCK;
    for (int i = blockIdx.x * BLOCK + threadIdx.x; i < n4; i += stride)
        o4[i] = z;
}

// T % 4 == 0 path: each thread loads int4 (4 tokens, all in the same row).
__global__ __launch_bounds__(BLOCK)
void OneHotEncoder_43052752175267_scatter4(const int* __restrict__ tokens,
                                           float* __restrict__ out,
                                           int T, int total4) {
    const int idx = blockIdx.x * BLOCK + threadIdx.x;
    if (idx >= total4) return;
    const int4 t = ((const int4*)tokens)[idx];
    const int row = (idx * 4) / T;            // all 4 tokens in same row (T%4==0)
    float* orow = out + (long long)row * VOCAB;
    if (t.x != 0) atomicAdd(&orow[t.x], 1.0f);
    if (t.y != 0) atomicAdd(&orow[t.y], 1.0f);
    if (t.z != 0) atomicAdd(&orow[t.z], 1.0f);
    if (t.w != 0) atomicAdd(&orow[t.w], 1.0f);
}

// Fallback for odd T: one token per thread.
__global__ __launch_bounds__(BLOCK)
void OneHotEncoder_43052752175267_scatter1(const int* __restrict__ tokens,
                                           float* __restrict__ out,
                                           int T, int total) {
    const int idx = blockIdx.x * BLOCK + threadIdx.x;
    if (idx >= total) return;
    const int tok = tokens[idx];
    if (tok != 0)
        atomicAdd(&out[(long long)(idx / T) * VOCAB + tok], 1.0f);
}

extern "C" void kernel_launch(void* const* d_in, const int* in_sizes, int n_in,
                              void* d_out, int out_size, void* d_ws, size_t ws_size,
                              hipStream_t stream) {
    const int* tokens = (const int*)d_in[0];
    // d_in[1] (lengths) is unused by the reference computation.
    const int B = in_sizes[1];           // 256 (lengths has one entry per row)
    const int T = in_sizes[0] / B;       // 2048
    float* out = (float*)d_out;

    // Kernel 1: zero the output (B*VOCAB floats, VOCAB%4==0 -> n4 exact).
    const int n4 = (B * VOCAB) / 4;                       // 2,048,000 f32x4
    const int zgrid = 2048;                               // grid-stride, ~4 iters/thread
    OneHotEncoder_43052752175267_zero<<<dim3(zgrid), dim3(BLOCK), 0, stream>>>(out, n4);

    // Kernel 2: scatter-add the tokens.
    const int total = B * T;                              // 524,288 tokens
    if ((T & 3) == 0) {
        const int total4 = total / 4;                     // 131,072 int4
        const int sgrid = (total4 + BLOCK - 1) / BLOCK;   // 512 blocks
        OneHotEncoder_43052752175267_scatter4<<<dim3(sgrid), dim3(BLOCK), 0, stream>>>(
            tokens, out, T, total4);
    } else {
        const int sgrid = (total + BLOCK - 1) / BLOCK;
        OneHotEncoder_43052752175267_scatter1<<<dim3(sgrid), dim3(BLOCK), 0, stream>>>(
            tokens, out, T, total);
    }
}

// Round 4
// 66.266 us; speedup vs baseline: 1.3992x; 1.3992x over previous
//
#include <hip/hip_runtime.h>

// OneHotEncoder: per-row histogram of tokens, skipping pad_idx=0.
// tokens: [B=256, T=2048] int32 ; out: [B, VOCAB=32000] float32.
//
// V4: single kernel, vocab-chunked LDS histogram. Lessons so far:
//  - global atomic scatter (V3) costs ~25-30 us: random 4B L2-line RMWs
//    serialize. LDS histogram + streamed store is the right structure.
//  - nontemporal stores (V2) were neutral-to-negative vs normal stores:
//    the 6.2 TB/s harness fill uses the normal path; NT drains slower.
//  - measured floor includes a fixed ~43 us 268MB harness poison fill.
// V4 changes vs V2: CHUNKS 4->8 (8KB LDS -> 8 blocks/CU, the wave limit),
// normal f32x4 stores, int4 token loads, and row = bid % B so all 8 chunks
// of a row share an XCD (one L2 fetch of the row serves all 8 blocks).

#define VOCAB  32000
#define CHUNKS 8
#define CV     (VOCAB / CHUNKS)   // 4000 vocab entries per chunk
#define BLOCK  256

__global__ __launch_bounds__(BLOCK)
void OneHotEncoder_43052752175267_kernel(const int* __restrict__ tokens,
                                         float* __restrict__ out,
                                         int T, int B) {
    // Packed histogram: hist[i] = counts for local tokens 2i (lo16), 2i+1 (hi16).
    // Max count = T = 2048 < 65536 -> no carry into the neighboring half.
    __shared__ __align__(16) unsigned int hist[CV / 2];   // 2000 u32 = 8 KB

    const int row   = blockIdx.x % B;     // consecutive bids = same chunk,
    const int chunk = blockIdx.x / B;     // consecutive rows -> row's 8 chunks
    const int lo    = chunk * CV;         // all map to XCD row%8 (B%8==0)
    const int tid   = threadIdx.x;

    // --- Phase 1: zero the LDS histogram ---
    uint4* h4 = (uint4*)hist;
    const uint4 z = make_uint4(0u, 0u, 0u, 0u);
    for (int i = tid; i < CV / 8; i += BLOCK)      // 500 uint4 -> 2 iters
        h4[i] = z;
    __syncthreads();

    // --- Phase 2: scan this row's tokens (int4 loads), DS-atomic in-range ones ---
    const int* trow = tokens + (long long)row * T;
    const int nt4 = T >> 2;
    const int4* t4 = (const int4*)trow;
    for (int i = tid; i < nt4; i += BLOCK) {       // 2 iters at T=2048
        int4 t = t4[i];
        unsigned l0 = (unsigned)(t.x - lo);
        unsigned l1 = (unsigned)(t.y - lo);
        unsigned l2 = (unsigned)(t.z - lo);
        unsigned l3 = (unsigned)(t.w - lo);
        if (t.x != 0 && l0 < (unsigned)CV) atomicAdd(&hist[l0 >> 1], 1u << ((l0 & 1) << 4));
        if (t.y != 0 && l1 < (unsigned)CV) atomicAdd(&hist[l1 >> 1], 1u << ((l1 & 1) << 4));
        if (t.z != 0 && l2 < (unsigned)CV) atomicAdd(&hist[l2 >> 1], 1u << ((l2 & 1) << 4));
        if (t.w != 0 && l3 < (unsigned)CV) atomicAdd(&hist[l3 >> 1], 1u << ((l3 & 1) << 4));
    }
    for (int i = (nt4 << 2) + tid; i < T; i += BLOCK) {   // tail if T%4 != 0
        int tok = trow[i];
        unsigned local = (unsigned)(tok - lo);
        if (tok != 0 && local < (unsigned)CV)
            atomicAdd(&hist[local >> 1], 1u << ((local & 1) << 4));
    }
    __syncthreads();

    // --- Phase 3: unpack and stream out, coalesced float4 stores (normal path) ---
    float4* o4 = (float4*)(out + (long long)row * VOCAB + lo);
    const uint2* h2 = (const uint2*)hist;
    for (int i = tid; i < CV / 4; i += BLOCK) {    // 1000 float4 -> 4 iters
        uint2 h = h2[i];
        float4 f;
        f.x = (float)(h.x & 0xFFFFu);
        f.y = (float)(h.x >> 16);
        f.z = (float)(h.y & 0xFFFFu);
        f.w = (float)(h.y >> 16);
        o4[i] = f;
    }
}

extern "C" void kernel_launch(void* const* d_in, const int* in_sizes, int n_in,
                              void* d_out, int out_size, void* d_ws, size_t ws_size,
                              hipStream_t stream) {
    const int* tokens = (const int*)d_in[0];
    // d_in[1] (lengths) is unused by the reference computation.
    const int B = in_sizes[1];           // 256 (lengths has one entry per row)
    const int T = in_sizes[0] / B;       // 2048
    float* out = (float*)d_out;

    OneHotEncoder_43052752175267_kernel<<<dim3(B * CHUNKS), dim3(BLOCK), 0, stream>>>(
        tokens, out, T, B);
}